// Round 6
// baseline (192.402 us; speedup 1.0000x reference)
//
#include <hip/hip_runtime.h>
#include <hip/hip_fp16.h>

// Problem constants
#define NN    256   // NUM_NODES
#define SS    4     // NUM_FSM_STATES
#define TT    3     // NUM_EDGE_TYPES
#define VV    4     // NUM_VARIANTS
#define NTY   8     // NUM_NODE_TYPES
#define NAC   15    // n_actions = T*S + 3
#define CAPG  48    // max packed pair-groups per col (96 edges; deg~Poi(38.4))
#define CAPE  (CAPG * 2)
#define ROWB  40    // bytes per tmp row (12 halves used + pad) -- r1-verified
#define ZROWB (NN * ROWB)       // zero pad row byte offset = 10240 (fits u16)
#define BUFB  (ZROWB + ROWB)    // bytes per tmp buffer
#define ZPK   ((unsigned)ZROWB | ((unsigned)ZROWB << 16))
#define GMR   16    // per-thread (per-parity-half) group regs; covers wave-max ~14

typedef _Float16 h2v __attribute__((ext_vector_type(2)));

#if defined(__has_builtin)
#if __has_builtin(__builtin_amdgcn_fdot2)
#define HAVE_FDOT2 1
#endif
#endif

static __device__ __forceinline__ unsigned ph2(float a, float b) {
    union { __half2 h; unsigned u; } c;
    c.h = __floats2half2_rn(a, b);
    return c.u;
}
static __device__ __forceinline__ h2v bch2(unsigned u) {
    union { unsigned u; h2v h; } c; c.u = u; return c.h;
}
static __device__ __forceinline__ float2 h2f2(unsigned u) {
    union { unsigned u; __half2 h; } c; c.u = u; return __half22float2(c.h);
}

// ---------------------------------------------------------------------------
// Setup:
//   blocks 0..767      : inv_deg row sums (coalesced, wave+LDS reduce)
//   blocks 768..831    : per-col edge build -> raw (row,type) list (u16),
//                        4 cols/block via float4 reads.  Bank-sort + pairing
//                        moved to k_sort (needs invperm).
//   block  832         : routing softmax
__global__ void k_setup(const float* __restrict__ adj,
                        const float* __restrict__ lrp,
                        float* __restrict__ inv_deg,
                        float* __restrict__ pol,
                        unsigned short* __restrict__ eoff,
                        int* __restrict__ ecnt) {
    const int b = blockIdx.x;
    const int tid = threadIdx.x;

    if (b < TT * NN) {
        __shared__ float wsum[4];
        float s = adj[(size_t)b * NN + tid];
#pragma unroll
        for (int off = 32; off > 0; off >>= 1) s += __shfl_down(s, off, 64);
        if ((tid & 63) == 0) wsum[tid >> 6] = s;
        __syncthreads();
        if (tid == 0)
            inv_deg[b] = 1.0f / fmaxf(wsum[0] + wsum[1] + wsum[2] + wsum[3], 1.0f);
    } else if (b < TT * NN + 64) {
        // edge lists for 4 columns: thread row=tid tests (t,tid,c4..c4+3)
        __shared__ int cnt[4];
        __shared__ unsigned short raw[4][CAPE];
        const int c4 = (b - TT * NN) * 4;
        if (tid < 4) cnt[tid] = 0;
        __syncthreads();
#pragma unroll
        for (int t = 0; t < TT; t++) {
            const float4 a4 = *(const float4*)(adj + ((size_t)t * NN + tid) * NN + c4);
            const float av[4] = {a4.x, a4.y, a4.z, a4.w};
#pragma unroll
            for (int c = 0; c < 4; c++) {
                if (av[c] != 0.f) {
                    int idx = atomicAdd(&cnt[c], 1);
                    if (idx < CAPE) raw[c][idx] = (unsigned short)((tid << 2) | t);
                }
            }
        }
        __syncthreads();
        const int c    = tid >> 6;       // one wave per column
        const int lane = tid & 63;
        int cc = cnt[c]; if (cc > CAPE) cc = CAPE;
        for (int j = lane; j < cc; j += 64)
            eoff[(size_t)(c4 + c) * CAPE + j] = raw[c][j];
        if (lane == 0) ecnt[c4 + c] = cc;
    } else {
        if (tid < VV * NTY * SS) {
            float x[NAC]; float m = -3.4e38f;
#pragma unroll
            for (int a = 0; a < NAC; a++) { x[a] = lrp[tid * NAC + a]; m = fmaxf(m, x[a]); }
            float ssum = 0.f;
#pragma unroll
            for (int a = 0; a < NAC; a++) { x[a] = __expf(x[a] - m); ssum += x[a]; }
            float inv = 1.f / ssum;
#pragma unroll
            for (int a = 0; a < NAC; a++) pol[tid * NAC + a] = x[a] * inv;
        }
    }
}

// ---------------------------------------------------------------------------
// k_sort: 1 block, 256 threads.
//  phase 0: counting sort of cols by group count -> perm, invperm.
//  phase 1 (thread q = rank, col = perm[q]):
//    - remap each edge (r,t) -> LDS byte offset invperm[r]*ROWB + t*8
//      (tmp rows are RANK-indexed in k_main -> phase-A writes conflict-free)
//    - bucket-sort edges by bank-pair key (5*invperm[r]+t) & 15
//    - rotate by rho = (q&15)*m/16 before pairing: at gather iter k the 16
//      cols of a 32-lane phase land on ~16 distinct bank-pairs
//    - pack pairs into epk, pad odd tail with ZROWB; gcnt = ceil(m/2)
__global__ void k_sort(const int* __restrict__ ecnt,
                       const unsigned short* __restrict__ eoff,
                       unsigned short* __restrict__ eoff2,
                       int* __restrict__ perm,
                       int* __restrict__ invperm,
                       unsigned* __restrict__ epk,
                       int* __restrict__ gcnt) {
    __shared__ int base[64];
    __shared__ unsigned short bins[256][16];
    const int tid = threadIdx.x;
    if (tid < 64) base[tid] = 0;
    __syncthreads();
    const int m0 = ecnt[tid];
    const int g0 = ((m0 + 1) >> 1) & 63;
    atomicAdd(&base[g0], 1);         // histogram by group count
    __syncthreads();
    if (tid == 0) {
        int s = 0;
#pragma unroll
        for (int b = 0; b < 64; b++) { int c = base[b]; base[b] = s; s += c; }
    }
    __syncthreads();
    const int pos = atomicAdd(&base[g0], 1);
    perm[pos] = tid;
    __syncthreads();
    invperm[perm[tid]] = tid;
    __syncthreads();

    // ---- phase 1: per-rank remap + bank-sort + rotate + pack ----
    const int q   = tid;
    const int col = perm[q];
    const int m   = ecnt[col];
    const unsigned short* src = eoff + (size_t)col * CAPE;
    unsigned short* dst = eoff2 + (size_t)col * CAPE;

#pragma unroll
    for (int bp = 0; bp < 16; bp++) bins[q][bp] = 0;
    // pass 1: count bank-pair keys
    for (int j = 0; j < m; j++) {
        const int rt = src[j];
        const int rr = invperm[rt >> 2], t = rt & 3;
        bins[q][(5 * rr + t) & 15]++;
    }
    // exclusive prefix (serial, private row)
    {
        int s = 0;
#pragma unroll
        for (int bp = 0; bp < 16; bp++) { int c = bins[q][bp]; bins[q][bp] = (unsigned short)s; s += c; }
    }
    // pass 2: place remapped offsets in bank-sorted order
    for (int j = 0; j < m; j++) {
        const int rt = src[j];
        const int rr = invperm[rt >> 2], t = rt & 3;
        const int key = (5 * rr + t) & 15;
        const int p = bins[q][key]++;
        dst[p] = (unsigned short)(rr * ROWB + t * 8);
    }
    // pass 3: rotate by rho, pair, pack
    const int rho = ((q & 15) * m) >> 4;
    const int G = (m + 1) >> 1;
    for (int g = 0; g < G; g++) {
        int p0 = 2 * g + rho;     if (p0 >= m) p0 -= m;
        unsigned a = dst[p0];
        unsigned bwd = (unsigned)ZROWB;
        if (2 * g + 1 < m) {
            int p1 = 2 * g + 1 + rho; if (p1 >= m) p1 -= m;
            bwd = dst[p1];
        }
        epk[(size_t)g * NN + col] = a | (bwd << 16);
    }
    gcnt[col] = G;
}

// ---------------------------------------------------------------------------
// Main loop: grid 512 = (e,i); block 512 threads = 2 threads per col.
// r1/r5-verified structure: col pair per lane pair, ROWB 40, b64 gather,
// chunk-2 scalar-branch loop, single barrier/step.
// This round: tmp rows indexed by RANK (write banks perfect again) and
// bank-sorted/staggered edge lists from k_sort (gather banks spread).
__global__ __launch_bounds__(512, 4) void k_main(
    const float* __restrict__ vw,
    const int* __restrict__ node_types,
    const float* __restrict__ pol,
    const float* __restrict__ inv_deg,
    const unsigned* __restrict__ epk,
    const int* __restrict__ gcnt,
    const int* __restrict__ perm,
    const int* __restrict__ steps_p,
    float* __restrict__ out)
{
    const int i    = blockIdx.x & 255;
    const int e    = blockIdx.x >> 8;
    const int tid  = threadIdx.x;
    const int rank = tid >> 1;          // LDS row index (conflict-free writes)
    const int col  = perm[rank];        // logical column (degree-sorted)
    const int h    = tid & 1;
    const int lane = tid & 63;
    const int wv   = tid >> 6;          // 8 waves
    const int steps = steps_p[0];

    __shared__ __align__(16) char tmpb[2 * BUFB];   // 20.6 KB
    __shared__ __align__(16) float backp[2][8];

    if (tid < 20) {
        int pb = tid / 10, w = tid % 10;
        ((unsigned*)(tmpb + pb * BUFB + ZROWB))[w] = 0u;
    }

    // --- per-(col,half) mixed policy slice, pre-scaled by inv_deg ---
    const float4 w4 = *(const float4*)(vw + ((size_t)i * NN + col) * VV);
    const float wvv[VV] = {w4.x, w4.y, w4.z, w4.w};
    const int ntj = node_types[col];
    const int ab  = h * 6;              // this half's action base
    float pm6[SS][6], pcb[SS];
#pragma unroll
    for (int s = 0; s < SS; s++) {
        pcb[s] = 0.f;
#pragma unroll
        for (int a = 0; a < 6; a++) pm6[s][a] = 0.f;
    }
#pragma unroll
    for (int v = 0; v < VV; v++) {
        const float* pr = pol + (size_t)(v * NTY + ntj) * SS * NAC;
#pragma unroll
        for (int s = 0; s < SS; s++) {
            const float* p = pr + s * NAC;
#pragma unroll
            for (int a = 0; a < 6; a++) pm6[s][a] = fmaf(wvv[v], p[ab + a], pm6[s][a]);
            pcb[s] = fmaf(wvv[v], p[12 + h], pcb[s]);   // h0: accept, h1: back
        }
    }
    {
        float invd[TT];
#pragma unroll
        for (int t = 0; t < TT; t++) invd[t] = inv_deg[t * NN + col];
#pragma unroll
        for (int s = 0; s < SS; s++)
#pragma unroll
            for (int a = 0; a < 6; a++) pm6[s][a] *= invd[(ab + a) >> 2];
    }

    float D0 = (0 == e && col == i) ? 1.f : 0.f;
    float D1 = (1 == e && col == i) ? 1.f : 0.f;
    float D2 = 0.f, D3 = 0.f;
    float acc = 0.f;

    // --- this half's edge list (groups with parity h) into registers ---
    const int g_all = gcnt[col];
    const int ch = (g_all - h + 1) >> 1;     // my group count
    int km = ch;
#pragma unroll
    for (int off = 32; off > 0; off >>= 1) {
        int o = __shfl_xor(km, off, 64);
        km = o > km ? o : km;
    }
    const int kmax = __builtin_amdgcn_readfirstlane(km);   // wave-uniform

    unsigned ep[GMR];
#pragma unroll
    for (int k = 0; k < GMR; k++) {
        unsigned pk = epk[(size_t)(2 * k + h) * NN + col];  // in-bounds; junk past g_all
        ep[k] = (2 * k + h < g_all) ? pk : ZPK;             // junk reads zero row (bcast)
    }

    const h2v S10 = {(_Float16)1.0f, (_Float16)0.0f};
    const h2v S01 = {(_Float16)0.0f, (_Float16)1.0f};
    char* const myrow0 = tmpb + rank * ROWB + h * 12;   // RANK-indexed rows

    for (int step = 0; step < steps; step++) {
        const int par = step & 1;
        char* const buf = tmpb + par * BUFB;

        // ---- phase A: accept(h0)/back(h1) + my 12B of the fp16 tmp row ----
        float r4 = D0 * pcb[0];
        r4 = fmaf(D1, pcb[1], r4); r4 = fmaf(D2, pcb[2], r4); r4 = fmaf(D3, pcb[3], r4);
        if (h == 0) acc += r4;
        float bj = h ? r4 : 0.f;

        float tv[6];
#pragma unroll
        for (int a = 0; a < 6; a++) {
            float x = D0 * pm6[0][a];
            x = fmaf(D1, pm6[1][a], x);
            x = fmaf(D2, pm6[2][a], x);
            x = fmaf(D3, pm6[3][a], x);
            tv[a] = x;
        }
        char* const myrow = myrow0 + par * BUFB;
        *(unsigned*)(myrow)     = ph2(tv[0], tv[1]);
        *(unsigned*)(myrow + 4) = ph2(tv[2], tv[3]);
        *(unsigned*)(myrow + 8) = ph2(tv[4], tv[5]);

#pragma unroll
        for (int off = 32; off > 0; off >>= 1) bj += __shfl_down(bj, off, 64);
        if (lane == 0) backp[par][wv] = bj;

        __syncthreads();   // the ONLY barrier per step

        // ---- phase B: gather, 2 groups per scalar branch (4 b64 in flight) ----
        float d0a = 0.f, d1a = 0.f, d2a = 0.f, d3a = 0.f;
        float d0b = 0.f, d1b = 0.f, d2b = 0.f, d3b = 0.f;
#pragma unroll
        for (int kc = 0; kc < GMR; kc += 2) {
            if (kc < kmax) {   // kmax in SGPR -> scalar branch, no VALU
                const unsigned pkA = ep[kc];
                const unsigned pkB = ep[kc + 1];
                const uint2 qA0 = *(const uint2*)(buf + (pkA & 0xffffu));
                const uint2 qA1 = *(const uint2*)(buf + (pkA >> 16));
                const uint2 qB0 = *(const uint2*)(buf + (pkB & 0xffffu));
                const uint2 qB1 = *(const uint2*)(buf + (pkB >> 16));
#ifdef HAVE_FDOT2
                d0a = __builtin_amdgcn_fdot2(bch2(qA0.x), S10, d0a, false);
                d1a = __builtin_amdgcn_fdot2(bch2(qA0.x), S01, d1a, false);
                d2a = __builtin_amdgcn_fdot2(bch2(qA0.y), S10, d2a, false);
                d3a = __builtin_amdgcn_fdot2(bch2(qA0.y), S01, d3a, false);
                d0a = __builtin_amdgcn_fdot2(bch2(qA1.x), S10, d0a, false);
                d1a = __builtin_amdgcn_fdot2(bch2(qA1.x), S01, d1a, false);
                d2a = __builtin_amdgcn_fdot2(bch2(qA1.y), S10, d2a, false);
                d3a = __builtin_amdgcn_fdot2(bch2(qA1.y), S01, d3a, false);
                d0b = __builtin_amdgcn_fdot2(bch2(qB0.x), S10, d0b, false);
                d1b = __builtin_amdgcn_fdot2(bch2(qB0.x), S01, d1b, false);
                d2b = __builtin_amdgcn_fdot2(bch2(qB0.y), S10, d2b, false);
                d3b = __builtin_amdgcn_fdot2(bch2(qB0.y), S01, d3b, false);
                d0b = __builtin_amdgcn_fdot2(bch2(qB1.x), S10, d0b, false);
                d1b = __builtin_amdgcn_fdot2(bch2(qB1.x), S01, d1b, false);
                d2b = __builtin_amdgcn_fdot2(bch2(qB1.y), S10, d2b, false);
                d3b = __builtin_amdgcn_fdot2(bch2(qB1.y), S01, d3b, false);
#else
                float2 f0 = h2f2(qA0.x), f1 = h2f2(qA0.y), f2 = h2f2(qA1.x), f3 = h2f2(qA1.y);
                d0a += f0.x + f2.x; d1a += f0.y + f2.y;
                d2a += f1.x + f3.x; d3a += f1.y + f3.y;
                float2 g0 = h2f2(qB0.x), g1 = h2f2(qB0.y), g2 = h2f2(qB1.x), g3 = h2f2(qB1.y);
                d0b += g0.x + g2.x; d1b += g0.y + g2.y;
                d2b += g1.x + g3.x; d3b += g1.y + g3.y;
#endif
            }
        }
        // rare tail beyond register capacity (per-lane guard vs junk entries)
        for (int k = GMR; k < kmax; k++) {
            unsigned pk = epk[(size_t)(2 * k + h) * NN + col];
            pk = (2 * k + h < g_all) ? pk : ZPK;
            const uint2 q0 = *(const uint2*)(buf + (pk & 0xffffu));
            const uint2 q1 = *(const uint2*)(buf + (pk >> 16));
            float2 f0 = h2f2(q0.x), f1 = h2f2(q0.y), f2 = h2f2(q1.x), f3 = h2f2(q1.y);
            d0a += f0.x + f2.x; d1a += f0.y + f2.y;
            d2a += f1.x + f3.x; d3a += f1.y + f3.y;
        }

        float d0 = d0a + d0b, d1 = d1a + d1b, d2 = d2a + d2b, d3 = d3a + d3b;

        // ---- combine the two halves of each col (same wave, lanes 2c/2c+1) ----
        d0 += __shfl_xor(d0, 1, 64);
        d1 += __shfl_xor(d1, 1, 64);
        d2 += __shfl_xor(d2, 1, 64);
        d3 += __shfl_xor(d3, 1, 64);

        // ---- restart (only the 2 col==i threads need `back`) ----
        if (col == i) {
            const float4 b0 = *(const float4*)(&backp[par][0]);
            const float4 b1 = *(const float4*)(&backp[par][4]);
            const float back = ((b0.x + b0.y) + (b0.z + b0.w)) +
                               ((b1.x + b1.y) + (b1.z + b1.w));
            if (e == 0) d0 = fmaf(back, 0.999f, d0);
            else        d1 = fmaf(back, 0.999f, d1);
        }
        D0 = d0; D1 = d1; D2 = d2; D3 = d3;
    }

    // final accept (h0 holds pacc and writes the output)
    float r4 = D0 * pcb[0];
    r4 = fmaf(D1, pcb[1], r4); r4 = fmaf(D2, pcb[2], r4); r4 = fmaf(D3, pcb[3], r4);
    if (h == 0) {
        acc += r4;
        out[((size_t)e * NN + i) * NN + col] = acc;
    }
}

// ---------------------------------------------------------------------------
extern "C" void kernel_launch(void* const* d_in, const int* in_sizes, int n_in,
                              void* d_out, int out_size, void* d_ws, size_t ws_size,
                              hipStream_t stream) {
    const float* vw  = (const float*)d_in[0];   // (N,N,V) fp32
    const float* adj = (const float*)d_in[1];   // (T,N,N) fp32 {0,1}
    const float* lrp = (const float*)d_in[2];   // (V,NTY,S,NAC) fp32
    const int* node_types = (const int*)d_in[3];
    const int* steps_p    = (const int*)d_in[4];

    float* ws            = (float*)d_ws;
    float* pol           = ws;                            // 1920 f
    float* inv_deg       = ws + 1920;                     // 768 f
    int*   gcnt          = (int*)(ws + 2688);             // 256 i
    unsigned* epk        = (unsigned*)(ws + 2944);        // CAPG*NN u32 = 48 KB
    int*   perm          = (int*)(ws + 2944 + CAPG * NN);           // 256 i
    int*   invperm       = (int*)(ws + 2944 + CAPG * NN + 256);     // 256 i
    int*   ecnt          = (int*)(ws + 2944 + CAPG * NN + 512);     // 256 i
    unsigned short* eoff  = (unsigned short*)(ws + 2944 + CAPG * NN + 768);   // CAPE*NN u16 = 48 KB
    unsigned short* eoff2 = eoff + (size_t)CAPE * NN;                         // CAPE*NN u16 = 48 KB

    k_setup<<<TT * NN + 64 + 1, 256, 0, stream>>>(adj, lrp, inv_deg, pol, eoff, ecnt);
    k_sort<<<1, 256, 0, stream>>>(ecnt, eoff, eoff2, perm, invperm, epk, gcnt);
    k_main<<<2 * NN, 512, 0, stream>>>(vw, node_types, pol, inv_deg, epk, gcnt,
                                       perm, steps_p, (float*)d_out);
}

// Round 7
// 160.629 us; speedup vs baseline: 1.1978x; 1.1978x over previous
//
#include <hip/hip_runtime.h>
#include <hip/hip_fp16.h>

// Problem constants
#define NN    256   // NUM_NODES
#define SS    4     // NUM_FSM_STATES
#define TT    3     // NUM_EDGE_TYPES
#define VV    4     // NUM_VARIANTS
#define NTY   8     // NUM_NODE_TYPES
#define NAC   15    // n_actions = T*S + 3
#define CAPG  48    // max packed pair-groups per col (96 edges; deg~Poi(38.4))
#define CAPE  (CAPG * 2)
#define ROWB  40    // bytes per tmp row (12 halves used + pad) -- r1-verified
#define ZROWB (NN * ROWB)       // zero pad row byte offset = 10240 (fits u16)
#define BUFB  (ZROWB + ROWB)    // bytes per tmp buffer = 10280 (< 64K imm)
#define ZPK   ((unsigned)ZROWB | ((unsigned)ZROWB << 16))
#define GMR   16    // per-thread (per-parity-half) group regs; covers wave-max ~14

typedef _Float16 h2v __attribute__((ext_vector_type(2)));

#if defined(__has_builtin)
#if __has_builtin(__builtin_amdgcn_fdot2)
#define HAVE_FDOT2 1
#endif
#endif

static __device__ __forceinline__ unsigned ph2(float a, float b) {
    union { __half2 h; unsigned u; } c;
    c.h = __floats2half2_rn(a, b);
    return c.u;
}
static __device__ __forceinline__ h2v bch2(unsigned u) {
    union { unsigned u; h2v h; } c; c.u = u; return c.h;
}
static __device__ __forceinline__ float2 h2f2(unsigned u) {
    union { unsigned u; __half2 h; } c; c.u = u; return __half22float2(c.h);
}

// ---------------------------------------------------------------------------
// Setup (r5-verified):
//   blocks 0..767      : inv_deg row sums (coalesced, wave+LDS reduce)
//   blocks 768..831    : per-col edge build, 4 cols/block via float4 reads
//   block  832         : routing softmax
__global__ void k_setup(const float* __restrict__ adj,
                        const float* __restrict__ lrp,
                        float* __restrict__ inv_deg,
                        float* __restrict__ pol,
                        unsigned* __restrict__ epk,
                        int* __restrict__ gcnt) {
    const int b = blockIdx.x;
    const int tid = threadIdx.x;

    if (b < TT * NN) {
        __shared__ float wsum[4];
        float s = adj[(size_t)b * NN + tid];
#pragma unroll
        for (int off = 32; off > 0; off >>= 1) s += __shfl_down(s, off, 64);
        if ((tid & 63) == 0) wsum[tid >> 6] = s;
        __syncthreads();
        if (tid == 0)
            inv_deg[b] = 1.0f / fmaxf(wsum[0] + wsum[1] + wsum[2] + wsum[3], 1.0f);
    } else if (b < TT * NN + 64) {
        // edge lists for 4 columns: thread row=tid tests (t,tid,c4..c4+3)
        __shared__ int cnt[4];
        __shared__ unsigned short offs[4][CAPE + 2];
        const int c4 = (b - TT * NN) * 4;
        if (tid < 4) cnt[tid] = 0;
        __syncthreads();
#pragma unroll
        for (int t = 0; t < TT; t++) {
            const float4 a4 = *(const float4*)(adj + ((size_t)t * NN + tid) * NN + c4);
            const float av[4] = {a4.x, a4.y, a4.z, a4.w};
#pragma unroll
            for (int c = 0; c < 4; c++) {
                if (av[c] != 0.f) {
                    int idx = atomicAdd(&cnt[c], 1);
                    if (idx < CAPE) offs[c][idx] = (unsigned short)(tid * ROWB + t * 8);
                }
            }
        }
        __syncthreads();
        const int c    = tid >> 6;       // one wave per column
        const int lane = tid & 63;
        int cc = cnt[c]; if (cc > CAPE) cc = CAPE;
        if (lane == 0 && (cc & 1)) offs[c][cc] = (unsigned short)ZROWB;  // pad odd
        __syncthreads();
        const int g = (cc + 1) >> 1;
        for (int gg = lane; gg < g; gg += 64)
            epk[(size_t)gg * NN + (c4 + c)] =
                (unsigned)offs[c][2 * gg] | ((unsigned)offs[c][2 * gg + 1] << 16);
        if (lane == 0) gcnt[c4 + c] = g;
    } else {
        if (tid < VV * NTY * SS) {
            float x[NAC]; float m = -3.4e38f;
#pragma unroll
            for (int a = 0; a < NAC; a++) { x[a] = lrp[tid * NAC + a]; m = fmaxf(m, x[a]); }
            float ssum = 0.f;
#pragma unroll
            for (int a = 0; a < NAC; a++) { x[a] = __expf(x[a] - m); ssum += x[a]; }
            float inv = 1.f / ssum;
#pragma unroll
            for (int a = 0; a < NAC; a++) pol[tid * NAC + a] = x[a] * inv;
        }
    }
}

// ---------------------------------------------------------------------------
// Degree sort (r5-verified, trivial): counting sort of the 256 cols by group
// count (ascending).  perm[rank] = col.  Waves of k_main hold degree-
// homogeneous columns, so the wave-max gather trip ~ local mean.
__global__ void k_sort(const int* __restrict__ gcnt, int* __restrict__ perm) {
    __shared__ int base[64];
    const int tid = threadIdx.x;
    if (tid < 64) base[tid] = 0;
    __syncthreads();
    const int g = gcnt[tid] & 63;
    atomicAdd(&base[g], 1);          // histogram
    __syncthreads();
    if (tid == 0) {
        int s = 0;
#pragma unroll
        for (int b = 0; b < 64; b++) { int c = base[b]; base[b] = s; s += c; }
    }
    __syncthreads();
    const int pos = atomicAdd(&base[g], 1);   // cursor within bin
    perm[pos] = tid;
}

// ---------------------------------------------------------------------------
// Main loop: grid 512 = (e,i); block 512 threads = 2 threads per col.
// r5-verified structure (105.9us): col pair per lane pair, ROWB 40, b64
// gather, chunk-2 scalar-branch loop, degree-sorted cols, 1 barrier/step.
// This round:
//  - __launch_bounds__(512, 2): grid is 2 blocks/CU, so the VGPR cap is 128,
//    not the 64 that (512,4) forced.  (2nd arg == min BLOCKS/CU empirically:
//    r2 (1024,8)->32+spill, r1 (512,4)->64, r3 (1024,2)->44 natural.)
//  - gather addresses pre-split into resident offA/offB registers (32 VGPR):
//    no v_and/v_lshr/v_add per ds_read.
//  - step loop unrolled x2 so par*BUFB folds into ds offset: immediates.
//  - dual accumulator sets restored.
__global__ __launch_bounds__(512, 2) void k_main(
    const float* __restrict__ vw,
    const int* __restrict__ node_types,
    const float* __restrict__ pol,
    const float* __restrict__ inv_deg,
    const unsigned* __restrict__ epk,
    const int* __restrict__ gcnt,
    const int* __restrict__ perm,
    const int* __restrict__ steps_p,
    float* __restrict__ out)
{
    const int i    = blockIdx.x & 255;
    const int e    = blockIdx.x >> 8;
    const int tid  = threadIdx.x;
    const int col  = perm[tid >> 1];    // degree-sorted column assignment
    const int h    = tid & 1;
    const int lane = tid & 63;
    const int wv   = tid >> 6;          // 8 waves
    const int steps = steps_p[0];

    __shared__ __align__(16) char tmpb[2 * BUFB];   // 20.6 KB
    __shared__ __align__(16) float backp[2][8];

    if (tid < 20) {
        int pb = tid / 10, w = tid % 10;
        ((unsigned*)(tmpb + pb * BUFB + ZROWB))[w] = 0u;
    }

    // --- per-(col,half) mixed policy slice, pre-scaled by inv_deg ---
    const float4 w4 = *(const float4*)(vw + ((size_t)i * NN + col) * VV);
    const float wvv[VV] = {w4.x, w4.y, w4.z, w4.w};
    const int ntj = node_types[col];
    const int ab  = h * 6;              // this half's action base
    float pm6[SS][6], pcb[SS];
#pragma unroll
    for (int s = 0; s < SS; s++) {
        pcb[s] = 0.f;
#pragma unroll
        for (int a = 0; a < 6; a++) pm6[s][a] = 0.f;
    }
#pragma unroll
    for (int v = 0; v < VV; v++) {
        const float* pr = pol + (size_t)(v * NTY + ntj) * SS * NAC;
#pragma unroll
        for (int s = 0; s < SS; s++) {
            const float* p = pr + s * NAC;
#pragma unroll
            for (int a = 0; a < 6; a++) pm6[s][a] = fmaf(wvv[v], p[ab + a], pm6[s][a]);
            pcb[s] = fmaf(wvv[v], p[12 + h], pcb[s]);   // h0: accept, h1: back
        }
    }
    {
        float invd[TT];
#pragma unroll
        for (int t = 0; t < TT; t++) invd[t] = inv_deg[t * NN + col];
#pragma unroll
        for (int s = 0; s < SS; s++)
#pragma unroll
            for (int a = 0; a < 6; a++) pm6[s][a] *= invd[(ab + a) >> 2];
    }

    float D0 = (0 == e && col == i) ? 1.f : 0.f;
    float D1 = (1 == e && col == i) ? 1.f : 0.f;
    float D2 = 0.f, D3 = 0.f;
    float acc = 0.f;

    // --- this half's edge list (groups with parity h), pre-split addresses ---
    const int g_all = gcnt[col];
    const int ch = (g_all - h + 1) >> 1;     // my group count
    int km = ch;
#pragma unroll
    for (int off = 32; off > 0; off >>= 1) {
        int o = __shfl_xor(km, off, 64);
        km = o > km ? o : km;
    }
    const int kmax = __builtin_amdgcn_readfirstlane(km);   // wave-uniform

    unsigned offA[GMR], offB[GMR];      // 32 VGPR: LDS byte offsets, base-free
#pragma unroll
    for (int k = 0; k < GMR; k++) {
        unsigned pk = epk[(size_t)(2 * k + h) * NN + col];  // in-bounds; junk past g_all
        pk = (2 * k + h < g_all) ? pk : ZPK;                // junk reads zero row (bcast)
        offA[k] = pk & 0xffffu;
        offB[k] = pk >> 16;
    }

    const h2v S10 = {(_Float16)1.0f, (_Float16)0.0f};
    const h2v S01 = {(_Float16)0.0f, (_Float16)1.0f};
    char* const myrow0 = tmpb + col * ROWB + h * 12;

    // One step with compile-time parity PAR: all LDS accesses get PAR*BUFB
    // folded into the ds offset: immediate (10280 < 64K).
#define STEP_BODY(PAR)                                                        \
    {                                                                         \
        float r4 = D0 * pcb[0];                                               \
        r4 = fmaf(D1, pcb[1], r4); r4 = fmaf(D2, pcb[2], r4);                 \
        r4 = fmaf(D3, pcb[3], r4);                                            \
        if (h == 0) acc += r4;                                                \
        float bj = h ? r4 : 0.f;                                              \
        float tv[6];                                                          \
        _Pragma("unroll")                                                     \
        for (int a = 0; a < 6; a++) {                                         \
            float x = D0 * pm6[0][a];                                         \
            x = fmaf(D1, pm6[1][a], x);                                       \
            x = fmaf(D2, pm6[2][a], x);                                       \
            x = fmaf(D3, pm6[3][a], x);                                       \
            tv[a] = x;                                                        \
        }                                                                     \
        *(unsigned*)(myrow0 + (PAR) * BUFB)     = ph2(tv[0], tv[1]);          \
        *(unsigned*)(myrow0 + (PAR) * BUFB + 4) = ph2(tv[2], tv[3]);          \
        *(unsigned*)(myrow0 + (PAR) * BUFB + 8) = ph2(tv[4], tv[5]);          \
        _Pragma("unroll")                                                     \
        for (int off = 32; off > 0; off >>= 1) bj += __shfl_down(bj, off, 64);\
        if (lane == 0) backp[PAR][wv] = bj;                                   \
        __syncthreads();                                                      \
        float d0a = 0.f, d1a = 0.f, d2a = 0.f, d3a = 0.f;                     \
        float d0b = 0.f, d1b = 0.f, d2b = 0.f, d3b = 0.f;                     \
        _Pragma("unroll")                                                     \
        for (int kc = 0; kc < GMR; kc += 2) {                                 \
            if (kc < kmax) {                                                  \
                const uint2 qA0 = *(const uint2*)(tmpb + (PAR) * BUFB + offA[kc]);     \
                const uint2 qA1 = *(const uint2*)(tmpb + (PAR) * BUFB + offB[kc]);     \
                const uint2 qB0 = *(const uint2*)(tmpb + (PAR) * BUFB + offA[kc + 1]); \
                const uint2 qB1 = *(const uint2*)(tmpb + (PAR) * BUFB + offB[kc + 1]); \
                GATHER8(qA0, qA1, a)                                          \
                GATHER8(qB0, qB1, b)                                          \
            }                                                                 \
        }                                                                     \
        for (int k = GMR; k < kmax; k++) {                                    \
            unsigned pk = epk[(size_t)(2 * k + h) * NN + col];                \
            pk = (2 * k + h < g_all) ? pk : ZPK;                              \
            const char* buf = tmpb + (PAR) * BUFB;                            \
            const uint2 q0 = *(const uint2*)(buf + (pk & 0xffffu));           \
            const uint2 q1 = *(const uint2*)(buf + (pk >> 16));               \
            float2 f0 = h2f2(q0.x), f1 = h2f2(q0.y);                          \
            float2 f2 = h2f2(q1.x), f3 = h2f2(q1.y);                          \
            d0a += f0.x + f2.x; d1a += f0.y + f2.y;                           \
            d2a += f1.x + f3.x; d3a += f1.y + f3.y;                           \
        }                                                                     \
        float d0 = d0a + d0b, d1 = d1a + d1b;                                 \
        float d2 = d2a + d2b, d3 = d3a + d3b;                                 \
        d0 += __shfl_xor(d0, 1, 64);                                          \
        d1 += __shfl_xor(d1, 1, 64);                                          \
        d2 += __shfl_xor(d2, 1, 64);                                          \
        d3 += __shfl_xor(d3, 1, 64);                                          \
        if (col == i) {                                                       \
            const float4 b0 = *(const float4*)(&backp[PAR][0]);               \
            const float4 b1 = *(const float4*)(&backp[PAR][4]);               \
            const float back = ((b0.x + b0.y) + (b0.z + b0.w)) +              \
                               ((b1.x + b1.y) + (b1.z + b1.w));               \
            if (e == 0) d0 = fmaf(back, 0.999f, d0);                          \
            else        d1 = fmaf(back, 0.999f, d1);                          \
        }                                                                     \
        D0 = d0; D1 = d1; D2 = d2; D3 = d3;                                   \
    }

#ifdef HAVE_FDOT2
#define GATHER8(q0, q1, SET)                                                  \
    d0##SET = __builtin_amdgcn_fdot2(bch2(q0.x), S10, d0##SET, false);        \
    d1##SET = __builtin_amdgcn_fdot2(bch2(q0.x), S01, d1##SET, false);        \
    d2##SET = __builtin_amdgcn_fdot2(bch2(q0.y), S10, d2##SET, false);        \
    d3##SET = __builtin_amdgcn_fdot2(bch2(q0.y), S01, d3##SET, false);        \
    d0##SET = __builtin_amdgcn_fdot2(bch2(q1.x), S10, d0##SET, false);        \
    d1##SET = __builtin_amdgcn_fdot2(bch2(q1.x), S01, d1##SET, false);        \
    d2##SET = __builtin_amdgcn_fdot2(bch2(q1.y), S10, d2##SET, false);        \
    d3##SET = __builtin_amdgcn_fdot2(bch2(q1.y), S01, d3##SET, false);
#else
#define GATHER8(q0, q1, SET)                                                  \
    {                                                                         \
        float2 f0 = h2f2(q0.x), f1 = h2f2(q0.y);                              \
        float2 f2 = h2f2(q1.x), f3 = h2f2(q1.y);                              \
        d0##SET += f0.x + f2.x; d1##SET += f0.y + f2.y;                       \
        d2##SET += f1.x + f3.x; d3##SET += f1.y + f3.y;                       \
    }
#endif

    for (int it = 0; it < steps; ) {
        STEP_BODY(0)
        ++it;
        if (it >= steps) break;
        STEP_BODY(1)
        ++it;
    }
#undef STEP_BODY
#undef GATHER8

    // final accept (h0 holds pacc and writes the output)
    float r4 = D0 * pcb[0];
    r4 = fmaf(D1, pcb[1], r4); r4 = fmaf(D2, pcb[2], r4); r4 = fmaf(D3, pcb[3], r4);
    if (h == 0) {
        acc += r4;
        out[((size_t)e * NN + i) * NN + col] = acc;
    }
}

// ---------------------------------------------------------------------------
extern "C" void kernel_launch(void* const* d_in, const int* in_sizes, int n_in,
                              void* d_out, int out_size, void* d_ws, size_t ws_size,
                              hipStream_t stream) {
    const float* vw  = (const float*)d_in[0];   // (N,N,V) fp32
    const float* adj = (const float*)d_in[1];   // (T,N,N) fp32 {0,1}
    const float* lrp = (const float*)d_in[2];   // (V,NTY,S,NAC) fp32
    const int* node_types = (const int*)d_in[3];
    const int* steps_p    = (const int*)d_in[4];

    float* ws       = (float*)d_ws;
    float* pol      = ws;                        // 1920 f
    float* inv_deg  = ws + 1920;                 // 768 f
    int*   gcnt     = (int*)(ws + 2688);         // 256 i
    unsigned* epk   = (unsigned*)(ws + 2944);    // CAPG*NN u32 = 48 KB
    int*   perm     = (int*)(ws + 2944 + CAPG * NN);  // 256 i

    k_setup<<<TT * NN + 64 + 1, 256, 0, stream>>>(adj, lrp, inv_deg, pol, epk, gcnt);
    k_sort<<<1, 256, 0, stream>>>(gcnt, perm);
    k_main<<<2 * NN, 512, 0, stream>>>(vw, node_types, pol, inv_deg, epk, gcnt,
                                       perm, steps_p, (float*)d_out);
}

// Round 8
// 153.837 us; speedup vs baseline: 1.2507x; 1.0442x over previous
//
#include <hip/hip_runtime.h>
#include <hip/hip_fp16.h>

// Problem constants
#define NN    256   // NUM_NODES
#define SS    4     // NUM_FSM_STATES
#define TT    3     // NUM_EDGE_TYPES
#define VV    4     // NUM_VARIANTS
#define NTY   8     // NUM_NODE_TYPES
#define NAC   15    // n_actions = T*S + 3
#define CAPG  48    // max packed pair-groups per col (96 edges; deg~Poi(38.4))
#define CAPE  (CAPG * 2)
#define ROWB  40    // bytes per tmp row (12 halves used + pad) -- r1-verified
#define ZROWB (NN * ROWB)       // zero pad row byte offset = 10240 (fits u16)
#define BUFB  (ZROWB + ROWB)    // bytes per tmp buffer = 10280 (8-aligned)
#define ZPK   ((unsigned)ZROWB | ((unsigned)ZROWB << 16))
#define GMR   16    // per-thread (per-parity-half) group regs; covers wave-max ~14

typedef _Float16 h2v __attribute__((ext_vector_type(2)));

#if defined(__has_builtin)
#if __has_builtin(__builtin_amdgcn_fdot2)
#define HAVE_FDOT2 1
#endif
#endif

static __device__ __forceinline__ unsigned ph2(float a, float b) {
    union { __half2 h; unsigned u; } c;
    c.h = __floats2half2_rn(a, b);
    return c.u;
}
static __device__ __forceinline__ h2v bch2(unsigned u) {
    union { unsigned u; h2v h; } c; c.u = u; return c.h;
}
static __device__ __forceinline__ float2 h2f2(unsigned u) {
    union { unsigned u; __half2 h; } c; c.u = u; return __half22float2(c.h);
}

// DPP-based lane combine: x + x[permuted lane], pure VALU (no ds_bpermute).
// quad_perm [1,0,3,2] = 0xB1 (xor1), [2,3,0,1] = 0x4E (xor2),
// row_ror:4 = 0x124, row_ror:8 = 0x128 (bijective within 16-lane row, so a
// full-row reduction is independent of exact shift direction semantics).
#define DPPADD(x, ctrl)                                                       \
    ((x) + __int_as_float(__builtin_amdgcn_update_dpp(                        \
               0, __float_as_int(x), (ctrl), 0xF, 0xF, true)))

// ---------------------------------------------------------------------------
// Setup (r5-verified):
//   blocks 0..767      : inv_deg row sums (coalesced, wave+LDS reduce)
//   blocks 768..831    : per-col edge build, 4 cols/block via float4 reads
//   block  832         : routing softmax
__global__ void k_setup(const float* __restrict__ adj,
                        const float* __restrict__ lrp,
                        float* __restrict__ inv_deg,
                        float* __restrict__ pol,
                        unsigned* __restrict__ epk,
                        int* __restrict__ gcnt) {
    const int b = blockIdx.x;
    const int tid = threadIdx.x;

    if (b < TT * NN) {
        __shared__ float wsum[4];
        float s = adj[(size_t)b * NN + tid];
#pragma unroll
        for (int off = 32; off > 0; off >>= 1) s += __shfl_down(s, off, 64);
        if ((tid & 63) == 0) wsum[tid >> 6] = s;
        __syncthreads();
        if (tid == 0)
            inv_deg[b] = 1.0f / fmaxf(wsum[0] + wsum[1] + wsum[2] + wsum[3], 1.0f);
    } else if (b < TT * NN + 64) {
        // edge lists for 4 columns: thread row=tid tests (t,tid,c4..c4+3)
        __shared__ int cnt[4];
        __shared__ unsigned short offs[4][CAPE + 2];
        const int c4 = (b - TT * NN) * 4;
        if (tid < 4) cnt[tid] = 0;
        __syncthreads();
#pragma unroll
        for (int t = 0; t < TT; t++) {
            const float4 a4 = *(const float4*)(adj + ((size_t)t * NN + tid) * NN + c4);
            const float av[4] = {a4.x, a4.y, a4.z, a4.w};
#pragma unroll
            for (int c = 0; c < 4; c++) {
                if (av[c] != 0.f) {
                    int idx = atomicAdd(&cnt[c], 1);
                    if (idx < CAPE) offs[c][idx] = (unsigned short)(tid * ROWB + t * 8);
                }
            }
        }
        __syncthreads();
        const int c    = tid >> 6;       // one wave per column
        const int lane = tid & 63;
        int cc = cnt[c]; if (cc > CAPE) cc = CAPE;
        if (lane == 0 && (cc & 1)) offs[c][cc] = (unsigned short)ZROWB;  // pad odd
        __syncthreads();
        const int g = (cc + 1) >> 1;
        for (int gg = lane; gg < g; gg += 64)
            epk[(size_t)gg * NN + (c4 + c)] =
                (unsigned)offs[c][2 * gg] | ((unsigned)offs[c][2 * gg + 1] << 16);
        if (lane == 0) gcnt[c4 + c] = g;
    } else {
        if (tid < VV * NTY * SS) {
            float x[NAC]; float m = -3.4e38f;
#pragma unroll
            for (int a = 0; a < NAC; a++) { x[a] = lrp[tid * NAC + a]; m = fmaxf(m, x[a]); }
            float ssum = 0.f;
#pragma unroll
            for (int a = 0; a < NAC; a++) { x[a] = __expf(x[a] - m); ssum += x[a]; }
            float inv = 1.f / ssum;
#pragma unroll
            for (int a = 0; a < NAC; a++) pol[tid * NAC + a] = x[a] * inv;
        }
    }
}

// ---------------------------------------------------------------------------
// Degree sort (r5-verified, trivial): counting sort of the 256 cols by group
// count (ascending).  perm[rank] = col.
__global__ void k_sort(const int* __restrict__ gcnt, int* __restrict__ perm) {
    __shared__ int base[64];
    const int tid = threadIdx.x;
    if (tid < 64) base[tid] = 0;
    __syncthreads();
    const int g = gcnt[tid] & 63;
    atomicAdd(&base[g], 1);          // histogram
    __syncthreads();
    if (tid == 0) {
        int s = 0;
#pragma unroll
        for (int b = 0; b < 64; b++) { int c = base[b]; base[b] = s; s += c; }
    }
    __syncthreads();
    const int pos = atomicAdd(&base[g], 1);   // cursor within bin
    perm[pos] = tid;
}

// ---------------------------------------------------------------------------
// Main loop: grid 512 = (e,i); block 512 threads = 2 threads per col.
// r7 base (103.6us): degree-sorted cols, chunk-2 gather with pre-split
// resident addresses, x2-unrolled step loop (parity as ds immediate).
// This round: cut LDS-pipe instruction count ~27% --
//  - bj reduce: 4 DPP stages (VALU) + 2 shfl (was 6 shfl = 6 ds_bpermute)
//  - d-combine: DPP quad_perm xor1 add (VALU) (was 4 ds_bpermute)
//  - phase-A writes: b64+b32 with branch-free operand selects (was 3 b32)
__global__ __launch_bounds__(512, 2) void k_main(
    const float* __restrict__ vw,
    const int* __restrict__ node_types,
    const float* __restrict__ pol,
    const float* __restrict__ inv_deg,
    const unsigned* __restrict__ epk,
    const int* __restrict__ gcnt,
    const int* __restrict__ perm,
    const int* __restrict__ steps_p,
    float* __restrict__ out)
{
    const int i    = blockIdx.x & 255;
    const int e    = blockIdx.x >> 8;
    const int tid  = threadIdx.x;
    const int col  = perm[tid >> 1];    // degree-sorted column assignment
    const int h    = tid & 1;
    const int lane = tid & 63;
    const int wv   = tid >> 6;          // 8 waves
    const int steps = steps_p[0];

    __shared__ __align__(16) char tmpb[2 * BUFB];   // 20.6 KB
    __shared__ __align__(16) float backp[2][8];

    if (tid < 20) {
        int pb = tid / 10, w = tid % 10;
        ((unsigned*)(tmpb + pb * BUFB + ZROWB))[w] = 0u;
    }

    // --- per-(col,half) mixed policy slice, pre-scaled by inv_deg ---
    const float4 w4 = *(const float4*)(vw + ((size_t)i * NN + col) * VV);
    const float wvv[VV] = {w4.x, w4.y, w4.z, w4.w};
    const int ntj = node_types[col];
    const int ab  = h * 6;              // this half's action base
    float pm6[SS][6], pcb[SS];
#pragma unroll
    for (int s = 0; s < SS; s++) {
        pcb[s] = 0.f;
#pragma unroll
        for (int a = 0; a < 6; a++) pm6[s][a] = 0.f;
    }
#pragma unroll
    for (int v = 0; v < VV; v++) {
        const float* pr = pol + (size_t)(v * NTY + ntj) * SS * NAC;
#pragma unroll
        for (int s = 0; s < SS; s++) {
            const float* p = pr + s * NAC;
#pragma unroll
            for (int a = 0; a < 6; a++) pm6[s][a] = fmaf(wvv[v], p[ab + a], pm6[s][a]);
            pcb[s] = fmaf(wvv[v], p[12 + h], pcb[s]);   // h0: accept, h1: back
        }
    }
    {
        float invd[TT];
#pragma unroll
        for (int t = 0; t < TT; t++) invd[t] = inv_deg[t * NN + col];
#pragma unroll
        for (int s = 0; s < SS; s++)
#pragma unroll
            for (int a = 0; a < 6; a++) pm6[s][a] *= invd[(ab + a) >> 2];
    }

    float D0 = (0 == e && col == i) ? 1.f : 0.f;
    float D1 = (1 == e && col == i) ? 1.f : 0.f;
    float D2 = 0.f, D3 = 0.f;
    float acc = 0.f;

    // --- this half's edge list (groups with parity h), pre-split addresses ---
    const int g_all = gcnt[col];
    const int ch = (g_all - h + 1) >> 1;     // my group count
    int km = ch;
#pragma unroll
    for (int off = 32; off > 0; off >>= 1) {
        int o = __shfl_xor(km, off, 64);
        km = o > km ? o : km;
    }
    const int kmax = __builtin_amdgcn_readfirstlane(km);   // wave-uniform

    unsigned offA[GMR], offB[GMR];      // 32 VGPR: LDS byte offsets, base-free
#pragma unroll
    for (int k = 0; k < GMR; k++) {
        unsigned pk = epk[(size_t)(2 * k + h) * NN + col];  // in-bounds; junk past g_all
        pk = (2 * k + h < g_all) ? pk : ZPK;                // junk reads zero row (bcast)
        offA[k] = pk & 0xffffu;
        offB[k] = pk >> 16;
    }

    const h2v S10 = {(_Float16)1.0f, (_Float16)0.0f};
    const h2v S01 = {(_Float16)0.0f, (_Float16)1.0f};
    // phase-A write addresses (branch-free split): b64 at +16h, b32 at +8+4h
    char* const myrowA = tmpb + col * ROWB + 16 * h;   // 8-aligned both h
    char* const myrowB = tmpb + col * ROWB + 8 + 4 * h;

#define STEP_BODY(PAR)                                                        \
    {                                                                         \
        float r4 = D0 * pcb[0];                                               \
        r4 = fmaf(D1, pcb[1], r4); r4 = fmaf(D2, pcb[2], r4);                 \
        r4 = fmaf(D3, pcb[3], r4);                                            \
        if (h == 0) acc += r4;                                                \
        float bj = h ? r4 : 0.f;                                              \
        float tv[6];                                                          \
        _Pragma("unroll")                                                     \
        for (int a = 0; a < 6; a++) {                                         \
            float x = D0 * pm6[0][a];                                         \
            x = fmaf(D1, pm6[1][a], x);                                       \
            x = fmaf(D2, pm6[2][a], x);                                       \
            x = fmaf(D3, pm6[3][a], x);                                       \
            tv[a] = x;                                                        \
        }                                                                     \
        {                                                                     \
            const unsigned wx = ph2(tv[0], tv[1]);                            \
            const unsigned wy = ph2(tv[2], tv[3]);                            \
            const unsigned wz = ph2(tv[4], tv[5]);                            \
            const unsigned lo = h ? wy : wx;                                  \
            const unsigned hi = h ? wz : wy;                                  \
            const unsigned bb = h ? wx : wz;                                  \
            *(unsigned long long*)(myrowA + (PAR) * BUFB) =                   \
                (unsigned long long)lo | ((unsigned long long)hi << 32);      \
            *(unsigned*)(myrowB + (PAR) * BUFB) = bb;                         \
        }                                                                     \
        bj = DPPADD(bj, 0xB1);    /* xor1 (quad_perm)          */             \
        bj = DPPADD(bj, 0x4E);    /* xor2 (quad_perm)          */             \
        bj = DPPADD(bj, 0x124);   /* row_ror:4                 */             \
        bj = DPPADD(bj, 0x128);   /* row_ror:8 -> row sums     */             \
        bj += __shfl_down(bj, 16, 64);                                        \
        bj += __shfl_down(bj, 32, 64);                                        \
        if (lane == 0) backp[PAR][wv] = bj;                                   \
        __syncthreads();                                                      \
        float d0a = 0.f, d1a = 0.f, d2a = 0.f, d3a = 0.f;                     \
        float d0b = 0.f, d1b = 0.f, d2b = 0.f, d3b = 0.f;                     \
        _Pragma("unroll")                                                     \
        for (int kc = 0; kc < GMR; kc += 2) {                                 \
            if (kc < kmax) {                                                  \
                const uint2 qA0 = *(const uint2*)(tmpb + (PAR) * BUFB + offA[kc]);     \
                const uint2 qA1 = *(const uint2*)(tmpb + (PAR) * BUFB + offB[kc]);     \
                const uint2 qB0 = *(const uint2*)(tmpb + (PAR) * BUFB + offA[kc + 1]); \
                const uint2 qB1 = *(const uint2*)(tmpb + (PAR) * BUFB + offB[kc + 1]); \
                GATHER8(qA0, qA1, a)                                          \
                GATHER8(qB0, qB1, b)                                          \
            }                                                                 \
        }                                                                     \
        for (int k = GMR; k < kmax; k++) {                                    \
            unsigned pk = epk[(size_t)(2 * k + h) * NN + col];                \
            pk = (2 * k + h < g_all) ? pk : ZPK;                              \
            const char* buf = tmpb + (PAR) * BUFB;                            \
            const uint2 q0 = *(const uint2*)(buf + (pk & 0xffffu));           \
            const uint2 q1 = *(const uint2*)(buf + (pk >> 16));               \
            float2 f0 = h2f2(q0.x), f1 = h2f2(q0.y);                          \
            float2 f2 = h2f2(q1.x), f3 = h2f2(q1.y);                          \
            d0a += f0.x + f2.x; d1a += f0.y + f2.y;                           \
            d2a += f1.x + f3.x; d3a += f1.y + f3.y;                           \
        }                                                                     \
        float d0 = d0a + d0b, d1 = d1a + d1b;                                 \
        float d2 = d2a + d2b, d3 = d3a + d3b;                                 \
        d0 = DPPADD(d0, 0xB1);   /* combine lane pair: VALU, no ds */         \
        d1 = DPPADD(d1, 0xB1);                                                \
        d2 = DPPADD(d2, 0xB1);                                                \
        d3 = DPPADD(d3, 0xB1);                                                \
        if (col == i) {                                                       \
            const float4 b0 = *(const float4*)(&backp[PAR][0]);               \
            const float4 b1 = *(const float4*)(&backp[PAR][4]);               \
            const float back = ((b0.x + b0.y) + (b0.z + b0.w)) +              \
                               ((b1.x + b1.y) + (b1.z + b1.w));               \
            if (e == 0) d0 = fmaf(back, 0.999f, d0);                          \
            else        d1 = fmaf(back, 0.999f, d1);                          \
        }                                                                     \
        D0 = d0; D1 = d1; D2 = d2; D3 = d3;                                   \
    }

#ifdef HAVE_FDOT2
#define GATHER8(q0, q1, SET)                                                  \
    d0##SET = __builtin_amdgcn_fdot2(bch2(q0.x), S10, d0##SET, false);        \
    d1##SET = __builtin_amdgcn_fdot2(bch2(q0.x), S01, d1##SET, false);        \
    d2##SET = __builtin_amdgcn_fdot2(bch2(q0.y), S10, d2##SET, false);        \
    d3##SET = __builtin_amdgcn_fdot2(bch2(q0.y), S01, d3##SET, false);        \
    d0##SET = __builtin_amdgcn_fdot2(bch2(q1.x), S10, d0##SET, false);        \
    d1##SET = __builtin_amdgcn_fdot2(bch2(q1.x), S01, d1##SET, false);        \
    d2##SET = __builtin_amdgcn_fdot2(bch2(q1.y), S10, d2##SET, false);        \
    d3##SET = __builtin_amdgcn_fdot2(bch2(q1.y), S01, d3##SET, false);
#else
#define GATHER8(q0, q1, SET)                                                  \
    {                                                                         \
        float2 f0 = h2f2(q0.x), f1 = h2f2(q0.y);                              \
        float2 f2 = h2f2(q1.x), f3 = h2f2(q1.y);                              \
        d0##SET += f0.x + f2.x; d1##SET += f0.y + f2.y;                       \
        d2##SET += f1.x + f3.x; d3##SET += f1.y + f3.y;                       \
    }
#endif

    for (int it = 0; it < steps; ) {
        STEP_BODY(0)
        ++it;
        if (it >= steps) break;
        STEP_BODY(1)
        ++it;
    }
#undef STEP_BODY
#undef GATHER8

    // final accept (h0 holds pacc and writes the output)
    float r4 = D0 * pcb[0];
    r4 = fmaf(D1, pcb[1], r4); r4 = fmaf(D2, pcb[2], r4); r4 = fmaf(D3, pcb[3], r4);
    if (h == 0) {
        acc += r4;
        out[((size_t)e * NN + i) * NN + col] = acc;
    }
}

// ---------------------------------------------------------------------------
extern "C" void kernel_launch(void* const* d_in, const int* in_sizes, int n_in,
                              void* d_out, int out_size, void* d_ws, size_t ws_size,
                              hipStream_t stream) {
    const float* vw  = (const float*)d_in[0];   // (N,N,V) fp32
    const float* adj = (const float*)d_in[1];   // (T,N,N) fp32 {0,1}
    const float* lrp = (const float*)d_in[2];   // (V,NTY,S,NAC) fp32
    const int* node_types = (const int*)d_in[3];
    const int* steps_p    = (const int*)d_in[4];

    float* ws       = (float*)d_ws;
    float* pol      = ws;                        // 1920 f
    float* inv_deg  = ws + 1920;                 // 768 f
    int*   gcnt     = (int*)(ws + 2688);         // 256 i
    unsigned* epk   = (unsigned*)(ws + 2944);    // CAPG*NN u32 = 48 KB
    int*   perm     = (int*)(ws + 2944 + CAPG * NN);  // 256 i

    k_setup<<<TT * NN + 64 + 1, 256, 0, stream>>>(adj, lrp, inv_deg, pol, epk, gcnt);
    k_sort<<<1, 256, 0, stream>>>(gcnt, perm);
    k_main<<<2 * NN, 512, 0, stream>>>(vw, node_types, pol, inv_deg, epk, gcnt,
                                       perm, steps_p, (float*)d_out);
}